// Round 9
// baseline (700.525 us; speedup 1.0000x reference)
//
#include <hip/hip_runtime.h>

#define D 128

typedef short bf16x8 __attribute__((ext_vector_type(8)));
typedef float f32x4 __attribute__((ext_vector_type(4)));

// bf16 helpers (finite values; RNE rounding)
static __device__ __forceinline__ unsigned short f2bf(float f) {
    unsigned int u = __float_as_uint(f);
    u = u + 0x7FFFu + ((u >> 16) & 1u);
    return (unsigned short)(u >> 16);
}
static __device__ __forceinline__ float bf2f(unsigned short h) {
    return __uint_as_float(((unsigned int)h) << 16);
}

// ---------------- CSR build ----------------

__global__ __launch_bounds__(256) void count_kernel(const int* __restrict__ dst,
        int* __restrict__ counts, int E) {
    int e = blockIdx.x * 256 + threadIdx.x;
    if (e < E) atomicAdd(&counts[dst[e]], 1);
}

__global__ __launch_bounds__(256) void scan_reduce(const int* __restrict__ counts,
        int* __restrict__ bsum, int n) {
    int b = blockIdx.x, t = threadIdx.x;
    int base = b * 1024 + t * 4;
    int s = 0;
    #pragma unroll
    for (int i = 0; i < 4; ++i) {
        int idx = base + i;
        if (idx < n) s += counts[idx];
    }
    __shared__ int sd[256];
    sd[t] = s;
    __syncthreads();
    #pragma unroll
    for (int off = 128; off > 0; off >>= 1) {
        if (t < off) sd[t] += sd[t + off];
        __syncthreads();
    }
    if (t == 0) bsum[b] = sd[0];
}

__global__ __launch_bounds__(64) void scan_tops(const int* __restrict__ bsum,
        int* __restrict__ bofs, int* __restrict__ row_ptr_end, int B) {
    int t = threadIdx.x;
    int v = (t < B) ? bsum[t] : 0;
    int inc = v;
    #pragma unroll
    for (int off = 1; off < 64; off <<= 1) {
        int u = __shfl_up(inc, off);
        if (t >= off) inc += u;
    }
    if (t < B) bofs[t] = inc - v;
    if (t == 63) *row_ptr_end = inc;
}

__global__ __launch_bounds__(256) void scan_final(const int* __restrict__ counts,
        const int* __restrict__ bofs, int* __restrict__ row_ptr,
        int* __restrict__ cursor, int n) {
    int b = blockIdx.x, t = threadIdx.x;
    int base = b * 1024 + t * 4;
    int v[4];
    int s = 0;
    #pragma unroll
    for (int i = 0; i < 4; ++i) {
        int idx = base + i;
        v[i] = (idx < n) ? counts[idx] : 0;
        s += v[i];
    }
    __shared__ int sd[256];
    sd[t] = s;
    __syncthreads();
    #pragma unroll
    for (int off = 1; off < 256; off <<= 1) {
        int u = (t >= off) ? sd[t - off] : 0;
        __syncthreads();
        sd[t] += u;
        __syncthreads();
    }
    int excl = bofs[b] + sd[t] - s;
    #pragma unroll
    for (int i = 0; i < 4; ++i) {
        int idx = base + i;
        if (idx < n) {
            row_ptr[idx] = excl;
            cursor[idx] = excl;
            excl += v[i];
        }
    }
}

__global__ __launch_bounds__(256) void fill_kernel(const int* __restrict__ src,
        const int* __restrict__ dst, int* __restrict__ cursor,
        int* __restrict__ src_sorted, int E) {
    int e = blockIdx.x * 256 + threadIdx.x;
    if (e < E) {
        int p = atomicAdd(&cursor[dst[e]], 1);
        src_sorted[p] = src[e];
    }
}

// ---------------- degree-bucket permutation (for divergence-free gather) ----------------

__global__ __launch_bounds__(256) void hist_kernel(const int* __restrict__ counts,
        int* __restrict__ hist, int n) {
    int i = blockIdx.x * 256 + threadIdx.x;
    if (i < n) atomicAdd(&hist[min(counts[i], 255)], 1);
}

__global__ __launch_bounds__(256) void scan_hist(const int* __restrict__ hist,
        int* __restrict__ binofs) {
    __shared__ int sd[256];
    int t = threadIdx.x;
    int v = hist[t];
    sd[t] = v;
    __syncthreads();
    #pragma unroll
    for (int off = 1; off < 256; off <<= 1) {
        int u = (t >= off) ? sd[t - off] : 0;
        __syncthreads();
        sd[t] += u;
        __syncthreads();
    }
    binofs[t] = sd[t] - v;
}

__global__ __launch_bounds__(256) void scatter_perm(const int* __restrict__ counts,
        int* __restrict__ binofs, int* __restrict__ perm, int n) {
    int i = blockIdx.x * 256 + threadIdx.x;
    if (i < n) {
        int b = min(counts[i], 255);
        int p = atomicAdd(&binofs[b], 1);
        perm[p] = i;
    }
}

// ---------------- f32 -> bf16 bulk convert ----------------

__global__ __launch_bounds__(256) void cvt_kernel(const float* __restrict__ in,
        unsigned short* __restrict__ out, int n4) {
    int i = blockIdx.x * 256 + threadIdx.x;
    if (i < n4) {
        float4 v = ((const float4*)in)[i];
        ushort4 o;
        o.x = f2bf(v.x); o.y = f2bf(v.y); o.z = f2bf(v.z); o.w = f2bf(v.w);
        ((ushort4*)out)[i] = o;
    }
}

// ---------------- W pack: hi/lo bf16 split in MFMA B-fragment order ----------------

__global__ __launch_bounds__(256) void pack_w(const float* __restrict__ W,
        unsigned short* __restrict__ Wp) {
    int t = blockIdx.x * 256 + threadIdx.x;   // 0..2047
    if (t >= 2048) return;
    int lane = t & 63;
    int ct = (t >> 6) & 7;
    int s = t >> 9;
    int n = ct * 16 + (lane & 15);
    int k0 = s * 32 + (lane >> 4) * 8;
    unsigned short hi[8], lo[8];
    #pragma unroll
    for (int j = 0; j < 8; ++j) {
        float f = W[(size_t)(k0 + j) * 128 + n];
        unsigned short h = f2bf(f);
        hi[j] = h;
        lo[j] = f2bf(f - bf2f(h));
    }
    size_t bh = ((size_t)((s * 8 + ct) * 2 + 0) * 64 + lane) * 8;
    size_t bl = ((size_t)((s * 8 + ct) * 2 + 1) * 64 + lane) * 8;
    #pragma unroll
    for (int j = 0; j < 8; ++j) { Wp[bh + j] = hi[j]; Wp[bl + j] = lo[j]; }
}

// ---------------- fused: Hout = relu(agg(Hin) @ W + b) [+ column mean] ----------------
// Slots are processed in degree-sorted order via perm: paired mode maps slot s
// -> node perm[s>>1] + (s&1)*N (pair = mirror node in shuffled graph, identical
// degree), so the 4 concurrent 16-lane groups of a wave carry near-identical
// edge-loop bounds (no exec-mask idle). Phase 1 (R6-proven): 16 lanes per node,
// lane reads uint4 chunk (16 B) of the 256 B src row, x8 unrolled with dual
// accumulator sets (8 loads in flight/lane). f32 sums -> LDS Af[64][129].
// Phase 2 (validated R4-R6): split-precision MFMA (hi/lo bf16, 3 MFMA per
// k-step) with prepacked Wp; epilogue scatters rows through nid[].

__global__ __launch_bounds__(256) void agg_gemm(const unsigned short* __restrict__ Hin,
        const int* __restrict__ row_ptr, const int* __restrict__ src_sorted,
        const int* __restrict__ perm,
        const unsigned short* __restrict__ Wp, const float* __restrict__ bias,
        unsigned short* __restrict__ Hout, int N, int NT, int paired,
        float* __restrict__ mean_out, int Nmean, float inv_n) {
    __shared__ float Af[64][129];
    __shared__ float red[4][128];
    __shared__ int nid[64];
    int tid = threadIdx.x;
    int bm = blockIdx.x * 64;

    if (tid < 64) {
        int s = bm + tid; if (s >= NT) s = NT - 1;
        nid[tid] = paired ? (perm[s >> 1] + (s & 1) * N) : perm[s];
    }
    __syncthreads();

    // ---- phase 1: gather 64 slots (16 concurrent x 4 iterations)
    {
        int lane = tid & 15;    // 16B chunk within 256B row
        int ng   = tid >> 4;    // slot group 0..15
        const uint4* h4 = (const uint4*)Hin;

        auto addv = [](float* a, uint4 v) {
            a[0] += __uint_as_float(v.x << 16);
            a[1] += __uint_as_float(v.x & 0xFFFF0000u);
            a[2] += __uint_as_float(v.y << 16);
            a[3] += __uint_as_float(v.y & 0xFFFF0000u);
            a[4] += __uint_as_float(v.z << 16);
            a[5] += __uint_as_float(v.z & 0xFFFF0000u);
            a[6] += __uint_as_float(v.w << 16);
            a[7] += __uint_as_float(v.w & 0xFFFF0000u);
        };

        #pragma unroll
        for (int g = 0; g < 4; ++g) {
            int local = g * 16 + ng;
            int node = nid[local];
            int base = (node >= N) ? N : 0;
            int rp = node - base;
            int beg = row_ptr[rp], end = row_ptr[rp + 1];

            float acc0[8], acc1[8];
            #pragma unroll
            for (int i = 0; i < 8; ++i) { acc0[i] = 0.f; acc1[i] = 0.f; }

            int j = beg;
            for (; j + 7 < end; j += 8) {
                uint4 v0 = h4[(size_t)(src_sorted[j    ] + base) * 16 + lane];
                uint4 v1 = h4[(size_t)(src_sorted[j + 1] + base) * 16 + lane];
                uint4 v2 = h4[(size_t)(src_sorted[j + 2] + base) * 16 + lane];
                uint4 v3 = h4[(size_t)(src_sorted[j + 3] + base) * 16 + lane];
                uint4 v4 = h4[(size_t)(src_sorted[j + 4] + base) * 16 + lane];
                uint4 v5 = h4[(size_t)(src_sorted[j + 5] + base) * 16 + lane];
                uint4 v6 = h4[(size_t)(src_sorted[j + 6] + base) * 16 + lane];
                uint4 v7 = h4[(size_t)(src_sorted[j + 7] + base) * 16 + lane];
                addv(acc0, v0); addv(acc1, v1); addv(acc0, v2); addv(acc1, v3);
                addv(acc0, v4); addv(acc1, v5); addv(acc0, v6); addv(acc1, v7);
            }
            if (j + 3 < end) {
                uint4 v0 = h4[(size_t)(src_sorted[j    ] + base) * 16 + lane];
                uint4 v1 = h4[(size_t)(src_sorted[j + 1] + base) * 16 + lane];
                uint4 v2 = h4[(size_t)(src_sorted[j + 2] + base) * 16 + lane];
                uint4 v3 = h4[(size_t)(src_sorted[j + 3] + base) * 16 + lane];
                addv(acc0, v0); addv(acc1, v1); addv(acc0, v2); addv(acc1, v3);
                j += 4;
            }
            if (j + 1 < end) {
                uint4 v0 = h4[(size_t)(src_sorted[j    ] + base) * 16 + lane];
                uint4 v1 = h4[(size_t)(src_sorted[j + 1] + base) * 16 + lane];
                addv(acc0, v0); addv(acc1, v1);
                j += 2;
            }
            if (j < end) {
                uint4 v0 = h4[(size_t)(src_sorted[j] + base) * 16 + lane];
                addv(acc0, v0);
            }
            #pragma unroll
            for (int i = 0; i < 8; ++i) Af[local][lane * 8 + i] = acc0[i] + acc1[i];
        }
    }
    __syncthreads();

    // ---- phase 2: split-precision MFMA from LDS A-tile
    int w = tid >> 6, l = tid & 63;
    int fr = l & 15;
    int kg = l >> 4;

    f32x4 acc[8];
    #pragma unroll
    for (int ct = 0; ct < 8; ++ct) acc[ct] = (f32x4){0.f, 0.f, 0.f, 0.f};

    const float* arow = &Af[w * 16 + fr][0];
    const uint4* wp4 = (const uint4*)Wp;

    for (int s = 0; s < 4; ++s) {
        bf16x8 a_hi, a_lo;
        #pragma unroll
        for (int jj = 0; jj < 8; ++jj) {
            float f = arow[s * 32 + kg * 8 + jj];
            unsigned short h = f2bf(f);
            a_hi[jj] = (short)h;
            a_lo[jj] = (short)f2bf(f - bf2f(h));
        }
        #pragma unroll
        for (int ct = 0; ct < 8; ++ct) {
            uint4 bhu = wp4[(size_t)((s * 8 + ct) * 2 + 0) * 64 + l];
            uint4 blu = wp4[(size_t)((s * 8 + ct) * 2 + 1) * 64 + l];
            bf16x8 b_hi, b_lo;
            *(uint4*)&b_hi = bhu;
            *(uint4*)&b_lo = blu;
            acc[ct] = __builtin_amdgcn_mfma_f32_16x16x32_bf16(a_hi, b_hi, acc[ct], 0, 0, 0);
            acc[ct] = __builtin_amdgcn_mfma_f32_16x16x32_bf16(a_lo, b_hi, acc[ct], 0, 0, 0);
            acc[ct] = __builtin_amdgcn_mfma_f32_16x16x32_bf16(a_hi, b_lo, acc[ct], 0, 0, 0);
        }
    }

    // ---- epilogue: bias + relu + bf16 scatter-store via nid (+ column sums)
    float colsum[8];
    #pragma unroll
    for (int ct = 0; ct < 8; ++ct) {
        int col = ct * 16 + fr;
        float b = bias[col];
        float cs = 0.f;
        #pragma unroll
        for (int r = 0; r < 4; ++r) {
            int lm = w * 16 + kg * 4 + r;       // local slot 0..63
            float v = fmaxf(acc[ct][r] + b, 0.f);
            if (bm + lm < NT) {
                int node = nid[lm];
                Hout[(size_t)node * 128 + col] = f2bf(v);
                if (node < Nmean) cs += v;
            }
        }
        colsum[ct] = cs;
    }

    if (mean_out) {
        #pragma unroll
        for (int ct = 0; ct < 8; ++ct) {
            float v = colsum[ct];
            v += __shfl_xor(v, 16);
            v += __shfl_xor(v, 32);
            if (l < 16) red[w][ct * 16 + l] = v;
        }
        __syncthreads();
        if (tid < 128) {
            float s = red[0][tid] + red[1][tid] + red[2][tid] + red[3][tid];
            if (s != 0.f) atomicAdd(&mean_out[tid], s * inv_n);
        }
    }
}

// ---------------- wsv = Wd @ s ----------------

__global__ __launch_bounds__(128) void wd_kernel(const float* __restrict__ Wd,
        const float* __restrict__ s, float* __restrict__ wsv) {
    __shared__ float sl[128];
    int i = threadIdx.x;
    sl[i] = s[i];
    __syncthreads();
    float acc = 0.f;
    for (int j = 0; j < 128; ++j) acc += Wd[(size_t)i * 128 + j] * sl[j];
    wsv[i] = acc;
}

// ---------------- out[i] = dot(h[i], wsv), h bf16, one wave per node ----------------

__global__ __launch_bounds__(256) void disc_kernel(const unsigned short* __restrict__ h,
        const float* __restrict__ wsv, float* __restrict__ out, int n) {
    int wave = threadIdx.x >> 6, lane = threadIdx.x & 63;
    int node = blockIdx.x * 4 + wave;
    if (node >= n) return;
    unsigned int hv = ((const unsigned int*)h)[(size_t)node * 64 + lane];
    float2 wv = *(const float2*)&wsv[lane * 2];
    float lo = __uint_as_float(hv << 16);
    float hi = __uint_as_float(hv & 0xFFFF0000u);
    float acc = lo * wv.x + hi * wv.y;
    #pragma unroll
    for (int off = 32; off > 0; off >>= 1) acc += __shfl_down(acc, off);
    if (lane == 0) out[node] = acc;
}

// ---------------- host orchestration ----------------

extern "C" void kernel_launch(void* const* d_in, const int* in_sizes, int n_in,
                              void* d_out, int out_size, void* d_ws, size_t ws_size,
                              hipStream_t stream) {
    const int* edge_index = (const int*)d_in[0];
    const float* x  = (const float*)d_in[1];
    const float* sx = (const float*)d_in[2];
    const float* W0 = (const float*)d_in[3];
    const float* b0 = (const float*)d_in[4];
    const float* W1 = (const float*)d_in[5];
    const float* b1 = (const float*)d_in[6];
    const float* W2 = (const float*)d_in[7];
    const float* b2 = (const float*)d_in[8];
    const float* Wd = (const float*)d_in[9];
    float* out = (float*)d_out;

    const int E = in_sizes[0] / 2;
    const int N = in_sizes[1] / D;
    const int* src = edge_index;
    const int* dst = edge_index + E;
    const float inv_n = 1.0f / (float)N;

    char* wsp = (char*)d_ws;
    size_t off = 0;
    auto alloc = [&](size_t bytes) -> void* {
        void* p = wsp + off;
        off += (bytes + 511) & ~(size_t)511;
        return p;
    };
    int* counts     = (int*)alloc((size_t)N * 4);
    int* row_ptr    = (int*)alloc((size_t)(N + 1) * 4);
    int* cursor     = (int*)alloc((size_t)N * 4);
    int* src_sorted = (int*)alloc((size_t)E * 4);
    int* bsum       = (int*)alloc(64 * 4);
    int* bofs       = (int*)alloc(64 * 4);
    int* hist       = (int*)alloc(256 * 4);
    int* binofs     = (int*)alloc(256 * 4);
    int* perm       = (int*)alloc((size_t)N * 4);
    float* svec     = (float*)alloc(D * 4);
    float* wsv      = (float*)alloc(D * 4);
    unsigned short* wp0 = (unsigned short*)alloc((size_t)D * D * 2 * 2);
    unsigned short* wp1 = (unsigned short*)alloc((size_t)D * D * 2 * 2);
    unsigned short* wp2 = (unsigned short*)alloc((size_t)D * D * 2 * 2);

    size_t fixed = off;
    size_t need_batched = fixed + 2 * ((size_t)2 * N * D * 2 + 512);
    bool batched = ws_size >= need_batched;
    int NB = batched ? 2 * N : N;
    int paired = batched ? 1 : 0;

    unsigned short* hbufA = (unsigned short*)alloc((size_t)NB * D * 2);
    unsigned short* hbufB = (unsigned short*)alloc((size_t)NB * D * 2);

    hipMemsetAsync(counts, 0, (size_t)N * 4, stream);
    hipMemsetAsync(hist, 0, 256 * 4, stream);
    hipMemsetAsync(svec, 0, D * 4, stream);

    pack_w<<<8, 256, 0, stream>>>(W0, wp0);
    pack_w<<<8, 256, 0, stream>>>(W1, wp1);
    pack_w<<<8, 256, 0, stream>>>(W2, wp2);

    int eblocks = (E + 255) / 256;
    int nblocks = (N + 255) / 256;
    int sblocks = (N + 1023) / 1024;
    count_kernel<<<eblocks, 256, 0, stream>>>(dst, counts, E);
    scan_reduce<<<sblocks, 256, 0, stream>>>(counts, bsum, N);
    scan_tops<<<1, 64, 0, stream>>>(bsum, bofs, row_ptr + N, sblocks);
    scan_final<<<sblocks, 256, 0, stream>>>(counts, bofs, row_ptr, cursor, N);
    fill_kernel<<<eblocks, 256, 0, stream>>>(src, dst, cursor, src_sorted, E);
    // degree-bucket permutation (order within a bucket is irrelevant to values)
    hist_kernel<<<nblocks, 256, 0, stream>>>(counts, hist, N);
    scan_hist<<<1, 256, 0, stream>>>(hist, binofs);
    scatter_perm<<<nblocks, 256, 0, stream>>>(counts, binofs, perm, N);

    int n4 = N * D / 4;
    int cblocks = (n4 + 255) / 256;
    int gblocks = (NB + 63) / 64;

    if (batched) {
        cvt_kernel<<<cblocks, 256, 0, stream>>>(x, hbufA, n4);
        cvt_kernel<<<cblocks, 256, 0, stream>>>(sx, hbufA + (size_t)N * D, n4);
        agg_gemm<<<gblocks, 256, 0, stream>>>(hbufA, row_ptr, src_sorted, perm, wp0, b0,
                                              hbufB, N, NB, paired, nullptr, 0, 0.f);
        agg_gemm<<<gblocks, 256, 0, stream>>>(hbufB, row_ptr, src_sorted, perm, wp1, b1,
                                              hbufA, N, NB, paired, nullptr, 0, 0.f);
        agg_gemm<<<gblocks, 256, 0, stream>>>(hbufA, row_ptr, src_sorted, perm, wp2, b2,
                                              hbufB, N, NB, paired, svec, N, inv_n);
        wd_kernel<<<1, 128, 0, stream>>>(Wd, svec, wsv);
        disc_kernel<<<(NB + 3) / 4, 256, 0, stream>>>(hbufB, wsv, out, NB);
    } else {
        auto encode = [&](const float* input, float* mean_out) {
            cvt_kernel<<<cblocks, 256, 0, stream>>>(input, hbufA, n4);
            agg_gemm<<<gblocks, 256, 0, stream>>>(hbufA, row_ptr, src_sorted, perm, wp0, b0,
                                                  hbufB, N, NB, paired, nullptr, 0, 0.f);
            agg_gemm<<<gblocks, 256, 0, stream>>>(hbufB, row_ptr, src_sorted, perm, wp1, b1,
                                                  hbufA, N, NB, paired, nullptr, 0, 0.f);
            agg_gemm<<<gblocks, 256, 0, stream>>>(hbufA, row_ptr, src_sorted, perm, wp2, b2,
                                                  hbufB, N, NB, paired, mean_out, mean_out ? N : 0, inv_n);
        };
        encode(x, svec);
        wd_kernel<<<1, 128, 0, stream>>>(Wd, svec, wsv);
        disc_kernel<<<(NB + 3) / 4, 256, 0, stream>>>(hbufB, wsv, out, NB);
        encode(sx, nullptr);
        disc_kernel<<<(NB + 3) / 4, 256, 0, stream>>>(hbufB, wsv, out + N, NB);
    }
}

// Round 10
// 389.920 us; speedup vs baseline: 1.7966x; 1.7966x over previous
//
#include <hip/hip_runtime.h>

#define D 128

typedef short bf16x8 __attribute__((ext_vector_type(8)));
typedef float f32x4 __attribute__((ext_vector_type(4)));

// bf16 helpers (finite values; RNE rounding)
static __device__ __forceinline__ unsigned short f2bf(float f) {
    unsigned int u = __float_as_uint(f);
    u = u + 0x7FFFu + ((u >> 16) & 1u);
    return (unsigned short)(u >> 16);
}
static __device__ __forceinline__ float bf2f(unsigned short h) {
    return __uint_as_float(((unsigned int)h) << 16);
}

// ---------------- CSR build ----------------

__global__ __launch_bounds__(256) void count_kernel(const int* __restrict__ dst,
        int* __restrict__ counts, int E) {
    int e = blockIdx.x * 256 + threadIdx.x;
    if (e < E) atomicAdd(&counts[dst[e]], 1);
}

__global__ __launch_bounds__(256) void scan_reduce(const int* __restrict__ counts,
        int* __restrict__ bsum, int n) {
    int b = blockIdx.x, t = threadIdx.x;
    int base = b * 1024 + t * 4;
    int s = 0;
    #pragma unroll
    for (int i = 0; i < 4; ++i) {
        int idx = base + i;
        if (idx < n) s += counts[idx];
    }
    __shared__ int sd[256];
    sd[t] = s;
    __syncthreads();
    #pragma unroll
    for (int off = 128; off > 0; off >>= 1) {
        if (t < off) sd[t] += sd[t + off];
        __syncthreads();
    }
    if (t == 0) bsum[b] = sd[0];
}

__global__ __launch_bounds__(64) void scan_tops(const int* __restrict__ bsum,
        int* __restrict__ bofs, int* __restrict__ row_ptr_end, int B) {
    int t = threadIdx.x;
    int v = (t < B) ? bsum[t] : 0;
    int inc = v;
    #pragma unroll
    for (int off = 1; off < 64; off <<= 1) {
        int u = __shfl_up(inc, off);
        if (t >= off) inc += u;
    }
    if (t < B) bofs[t] = inc - v;
    if (t == 63) *row_ptr_end = inc;
}

__global__ __launch_bounds__(256) void scan_final(const int* __restrict__ counts,
        const int* __restrict__ bofs, int* __restrict__ row_ptr,
        int* __restrict__ cursor, int n) {
    int b = blockIdx.x, t = threadIdx.x;
    int base = b * 1024 + t * 4;
    int v[4];
    int s = 0;
    #pragma unroll
    for (int i = 0; i < 4; ++i) {
        int idx = base + i;
        v[i] = (idx < n) ? counts[idx] : 0;
        s += v[i];
    }
    __shared__ int sd[256];
    sd[t] = s;
    __syncthreads();
    #pragma unroll
    for (int off = 1; off < 256; off <<= 1) {
        int u = (t >= off) ? sd[t - off] : 0;
        __syncthreads();
        sd[t] += u;
        __syncthreads();
    }
    int excl = bofs[b] + sd[t] - s;
    #pragma unroll
    for (int i = 0; i < 4; ++i) {
        int idx = base + i;
        if (idx < n) {
            row_ptr[idx] = excl;
            cursor[idx] = excl;
            excl += v[i];
        }
    }
}

__global__ __launch_bounds__(256) void fill_kernel(const int* __restrict__ src,
        const int* __restrict__ dst, int* __restrict__ cursor,
        int* __restrict__ src_sorted, int E) {
    int e = blockIdx.x * 256 + threadIdx.x;
    if (e < E) {
        int p = atomicAdd(&cursor[dst[e]], 1);
        src_sorted[p] = src[e];
    }
}

// ---------------- degree-bucket permutation (LDS-aggregated counting sort) ----------------

// per-block LDS histogram, then <=256 global atomics per block
__global__ __launch_bounds__(256) void hist_kernel(const int* __restrict__ counts,
        int* __restrict__ hist, int n) {
    __shared__ int lh[256];
    int t = threadIdx.x;
    lh[t] = 0;
    __syncthreads();
    int base = blockIdx.x * 1024 + t * 4;
    #pragma unroll
    for (int i = 0; i < 4; ++i) {
        int idx = base + i;
        if (idx < n) atomicAdd(&lh[min(counts[idx], 255)], 1);
    }
    __syncthreads();
    if (lh[t] > 0) atomicAdd(&hist[t], lh[t]);
}

// 256-bin exclusive scan -> binofs (kept) + bincur (working cursor for scatter)
__global__ __launch_bounds__(256) void scan_hist(const int* __restrict__ hist,
        int* __restrict__ binofs, int* __restrict__ bincur) {
    __shared__ int sd[256];
    int t = threadIdx.x;
    int v = hist[t];
    sd[t] = v;
    __syncthreads();
    #pragma unroll
    for (int off = 1; off < 256; off <<= 1) {
        int u = (t >= off) ? sd[t - off] : 0;
        __syncthreads();
        sd[t] += u;
        __syncthreads();
    }
    binofs[t] = sd[t] - v;
    bincur[t] = sd[t] - v;
}

// block: LDS hist -> one global atomicAdd per non-empty bin (range reserve)
// -> distribute block's elements via LDS cursors.
__global__ __launch_bounds__(256) void scatter_perm(const int* __restrict__ counts,
        int* __restrict__ bincur, int* __restrict__ perm, int n) {
    __shared__ int lh[256];
    __shared__ int lbase[256];
    int t = threadIdx.x;
    lh[t] = 0;
    __syncthreads();
    int base = blockIdx.x * 1024 + t * 4;
    int bin[4];
    #pragma unroll
    for (int i = 0; i < 4; ++i) {
        int idx = base + i;
        bin[i] = (idx < n) ? min(counts[idx], 255) : -1;
        if (bin[i] >= 0) atomicAdd(&lh[bin[i]], 1);
    }
    __syncthreads();
    lbase[t] = (lh[t] > 0) ? atomicAdd(&bincur[t], lh[t]) : 0;
    lh[t] = 0;
    __syncthreads();
    #pragma unroll
    for (int i = 0; i < 4; ++i) {
        if (bin[i] >= 0) {
            int r = atomicAdd(&lh[bin[i]], 1);
            perm[lbase[bin[i]] + r] = base + i;
        }
    }
}

// ---------------- f32 -> bf16 bulk convert ----------------

__global__ __launch_bounds__(256) void cvt_kernel(const float* __restrict__ in,
        unsigned short* __restrict__ out, int n4) {
    int i = blockIdx.x * 256 + threadIdx.x;
    if (i < n4) {
        float4 v = ((const float4*)in)[i];
        ushort4 o;
        o.x = f2bf(v.x); o.y = f2bf(v.y); o.z = f2bf(v.z); o.w = f2bf(v.w);
        ((ushort4*)out)[i] = o;
    }
}

// ---------------- W pack: hi/lo bf16 split in MFMA B-fragment order ----------------

__global__ __launch_bounds__(256) void pack_w(const float* __restrict__ W,
        unsigned short* __restrict__ Wp) {
    int t = blockIdx.x * 256 + threadIdx.x;   // 0..2047
    if (t >= 2048) return;
    int lane = t & 63;
    int ct = (t >> 6) & 7;
    int s = t >> 9;
    int n = ct * 16 + (lane & 15);
    int k0 = s * 32 + (lane >> 4) * 8;
    unsigned short hi[8], lo[8];
    #pragma unroll
    for (int j = 0; j < 8; ++j) {
        float f = W[(size_t)(k0 + j) * 128 + n];
        unsigned short h = f2bf(f);
        hi[j] = h;
        lo[j] = f2bf(f - bf2f(h));
    }
    size_t bh = ((size_t)((s * 8 + ct) * 2 + 0) * 64 + lane) * 8;
    size_t bl = ((size_t)((s * 8 + ct) * 2 + 1) * 64 + lane) * 8;
    #pragma unroll
    for (int j = 0; j < 8; ++j) { Wp[bh + j] = hi[j]; Wp[bl + j] = lo[j]; }
}

// ---------------- fused: Hout = relu(agg(Hin) @ W + b) [+ column mean] ----------------
// Slots processed in degree-sorted order via perm; paired mode: slot s ->
// node perm[s>>1] + (s&1)*N (mirror node, identical degree) so the 4
// concurrent 16-lane groups in a wave carry near-identical edge-loop bounds.
// Phase 1 (R6-proven): 16 lanes/node, uint4 (16B) per lane per edge, x8
// unroll with dual accumulators (8 loads in flight/lane). f32 -> Af[64][129].
// Phase 2 (validated R4-R6): split-precision MFMA (hi/lo bf16, 3 MFMA/k-step)
// with prepacked Wp; epilogue scatters rows through nid[].

__global__ __launch_bounds__(256) void agg_gemm(const unsigned short* __restrict__ Hin,
        const int* __restrict__ row_ptr, const int* __restrict__ src_sorted,
        const int* __restrict__ perm,
        const unsigned short* __restrict__ Wp, const float* __restrict__ bias,
        unsigned short* __restrict__ Hout, int N, int NT, int paired,
        float* __restrict__ mean_out, int Nmean, float inv_n) {
    __shared__ float Af[64][129];
    __shared__ float red[4][128];
    __shared__ int nid[64];
    int tid = threadIdx.x;
    int bm = blockIdx.x * 64;

    if (tid < 64) {
        int s = bm + tid; if (s >= NT) s = NT - 1;
        nid[tid] = paired ? (perm[s >> 1] + (s & 1) * N) : perm[s];
    }
    __syncthreads();

    // ---- phase 1: gather 64 slots (16 concurrent x 4 iterations)
    {
        int lane = tid & 15;    // 16B chunk within 256B row
        int ng   = tid >> 4;    // slot group 0..15
        const uint4* h4 = (const uint4*)Hin;

        auto addv = [](float* a, uint4 v) {
            a[0] += __uint_as_float(v.x << 16);
            a[1] += __uint_as_float(v.x & 0xFFFF0000u);
            a[2] += __uint_as_float(v.y << 16);
            a[3] += __uint_as_float(v.y & 0xFFFF0000u);
            a[4] += __uint_as_float(v.z << 16);
            a[5] += __uint_as_float(v.z & 0xFFFF0000u);
            a[6] += __uint_as_float(v.w << 16);
            a[7] += __uint_as_float(v.w & 0xFFFF0000u);
        };

        #pragma unroll
        for (int g = 0; g < 4; ++g) {
            int local = g * 16 + ng;
            int node = nid[local];
            int base = (node >= N) ? N : 0;
            int rp = node - base;
            int beg = row_ptr[rp], end = row_ptr[rp + 1];

            float acc0[8], acc1[8];
            #pragma unroll
            for (int i = 0; i < 8; ++i) { acc0[i] = 0.f; acc1[i] = 0.f; }

            int j = beg;
            for (; j + 7 < end; j += 8) {
                uint4 v0 = h4[(size_t)(src_sorted[j    ] + base) * 16 + lane];
                uint4 v1 = h4[(size_t)(src_sorted[j + 1] + base) * 16 + lane];
                uint4 v2 = h4[(size_t)(src_sorted[j + 2] + base) * 16 + lane];
                uint4 v3 = h4[(size_t)(src_sorted[j + 3] + base) * 16 + lane];
                uint4 v4 = h4[(size_t)(src_sorted[j + 4] + base) * 16 + lane];
                uint4 v5 = h4[(size_t)(src_sorted[j + 5] + base) * 16 + lane];
                uint4 v6 = h4[(size_t)(src_sorted[j + 6] + base) * 16 + lane];
                uint4 v7 = h4[(size_t)(src_sorted[j + 7] + base) * 16 + lane];
                addv(acc0, v0); addv(acc1, v1); addv(acc0, v2); addv(acc1, v3);
                addv(acc0, v4); addv(acc1, v5); addv(acc0, v6); addv(acc1, v7);
            }
            if (j + 3 < end) {
                uint4 v0 = h4[(size_t)(src_sorted[j    ] + base) * 16 + lane];
                uint4 v1 = h4[(size_t)(src_sorted[j + 1] + base) * 16 + lane];
                uint4 v2 = h4[(size_t)(src_sorted[j + 2] + base) * 16 + lane];
                uint4 v3 = h4[(size_t)(src_sorted[j + 3] + base) * 16 + lane];
                addv(acc0, v0); addv(acc1, v1); addv(acc0, v2); addv(acc1, v3);
                j += 4;
            }
            if (j + 1 < end) {
                uint4 v0 = h4[(size_t)(src_sorted[j    ] + base) * 16 + lane];
                uint4 v1 = h4[(size_t)(src_sorted[j + 1] + base) * 16 + lane];
                addv(acc0, v0); addv(acc1, v1);
                j += 2;
            }
            if (j < end) {
                uint4 v0 = h4[(size_t)(src_sorted[j] + base) * 16 + lane];
                addv(acc0, v0);
            }
            #pragma unroll
            for (int i = 0; i < 8; ++i) Af[local][lane * 8 + i] = acc0[i] + acc1[i];
        }
    }
    __syncthreads();

    // ---- phase 2: split-precision MFMA from LDS A-tile
    int w = tid >> 6, l = tid & 63;
    int fr = l & 15;
    int kg = l >> 4;

    f32x4 acc[8];
    #pragma unroll
    for (int ct = 0; ct < 8; ++ct) acc[ct] = (f32x4){0.f, 0.f, 0.f, 0.f};

    const float* arow = &Af[w * 16 + fr][0];
    const uint4* wp4 = (const uint4*)Wp;

    for (int s = 0; s < 4; ++s) {
        bf16x8 a_hi, a_lo;
        #pragma unroll
        for (int jj = 0; jj < 8; ++jj) {
            float f = arow[s * 32 + kg * 8 + jj];
            unsigned short h = f2bf(f);
            a_hi[jj] = (short)h;
            a_lo[jj] = (short)f2bf(f - bf2f(h));
        }
        #pragma unroll
        for (int ct = 0; ct < 8; ++ct) {
            uint4 bhu = wp4[(size_t)((s * 8 + ct) * 2 + 0) * 64 + l];
            uint4 blu = wp4[(size_t)((s * 8 + ct) * 2 + 1) * 64 + l];
            bf16x8 b_hi, b_lo;
            *(uint4*)&b_hi = bhu;
            *(uint4*)&b_lo = blu;
            acc[ct] = __builtin_amdgcn_mfma_f32_16x16x32_bf16(a_hi, b_hi, acc[ct], 0, 0, 0);
            acc[ct] = __builtin_amdgcn_mfma_f32_16x16x32_bf16(a_lo, b_hi, acc[ct], 0, 0, 0);
            acc[ct] = __builtin_amdgcn_mfma_f32_16x16x32_bf16(a_hi, b_lo, acc[ct], 0, 0, 0);
        }
    }

    // ---- epilogue: bias + relu + bf16 scatter-store via nid (+ column sums)
    float colsum[8];
    #pragma unroll
    for (int ct = 0; ct < 8; ++ct) {
        int col = ct * 16 + fr;
        float b = bias[col];
        float cs = 0.f;
        #pragma unroll
        for (int r = 0; r < 4; ++r) {
            int lm = w * 16 + kg * 4 + r;       // local slot 0..63
            float v = fmaxf(acc[ct][r] + b, 0.f);
            if (bm + lm < NT) {
                int node = nid[lm];
                Hout[(size_t)node * 128 + col] = f2bf(v);
                if (node < Nmean) cs += v;
            }
        }
        colsum[ct] = cs;
    }

    if (mean_out) {
        #pragma unroll
        for (int ct = 0; ct < 8; ++ct) {
            float v = colsum[ct];
            v += __shfl_xor(v, 16);
            v += __shfl_xor(v, 32);
            if (l < 16) red[w][ct * 16 + l] = v;
        }
        __syncthreads();
        if (tid < 128) {
            float s = red[0][tid] + red[1][tid] + red[2][tid] + red[3][tid];
            if (s != 0.f) atomicAdd(&mean_out[tid], s * inv_n);
        }
    }
}

// ---------------- wsv = Wd @ s ----------------

__global__ __launch_bounds__(128) void wd_kernel(const float* __restrict__ Wd,
        const float* __restrict__ s, float* __restrict__ wsv) {
    __shared__ float sl[128];
    int i = threadIdx.x;
    sl[i] = s[i];
    __syncthreads();
    float acc = 0.f;
    for (int j = 0; j < 128; ++j) acc += Wd[(size_t)i * 128 + j] * sl[j];
    wsv[i] = acc;
}

// ---------------- out[i] = dot(h[i], wsv), h bf16, one wave per node ----------------

__global__ __launch_bounds__(256) void disc_kernel(const unsigned short* __restrict__ h,
        const float* __restrict__ wsv, float* __restrict__ out, int n) {
    int wave = threadIdx.x >> 6, lane = threadIdx.x & 63;
    int node = blockIdx.x * 4 + wave;
    if (node >= n) return;
    unsigned int hv = ((const unsigned int*)h)[(size_t)node * 64 + lane];
    float2 wv = *(const float2*)&wsv[lane * 2];
    float lo = __uint_as_float(hv << 16);
    float hi = __uint_as_float(hv & 0xFFFF0000u);
    float acc = lo * wv.x + hi * wv.y;
    #pragma unroll
    for (int off = 32; off > 0; off >>= 1) acc += __shfl_down(acc, off);
    if (lane == 0) out[node] = acc;
}

// ---------------- host orchestration ----------------

extern "C" void kernel_launch(void* const* d_in, const int* in_sizes, int n_in,
                              void* d_out, int out_size, void* d_ws, size_t ws_size,
                              hipStream_t stream) {
    const int* edge_index = (const int*)d_in[0];
    const float* x  = (const float*)d_in[1];
    const float* sx = (const float*)d_in[2];
    const float* W0 = (const float*)d_in[3];
    const float* b0 = (const float*)d_in[4];
    const float* W1 = (const float*)d_in[5];
    const float* b1 = (const float*)d_in[6];
    const float* W2 = (const float*)d_in[7];
    const float* b2 = (const float*)d_in[8];
    const float* Wd = (const float*)d_in[9];
    float* out = (float*)d_out;

    const int E = in_sizes[0] / 2;
    const int N = in_sizes[1] / D;
    const int* src = edge_index;
    const int* dst = edge_index + E;
    const float inv_n = 1.0f / (float)N;

    char* wsp = (char*)d_ws;
    size_t off = 0;
    auto alloc = [&](size_t bytes) -> void* {
        void* p = wsp + off;
        off += (bytes + 511) & ~(size_t)511;
        return p;
    };
    int* counts     = (int*)alloc((size_t)N * 4);
    int* row_ptr    = (int*)alloc((size_t)(N + 1) * 4);
    int* cursor     = (int*)alloc((size_t)N * 4);
    int* src_sorted = (int*)alloc((size_t)E * 4);
    int* bsum       = (int*)alloc(64 * 4);
    int* bofs       = (int*)alloc(64 * 4);
    int* hist       = (int*)alloc(256 * 4);
    int* binofs     = (int*)alloc(256 * 4);
    int* bincur     = (int*)alloc(256 * 4);
    int* perm       = (int*)alloc((size_t)N * 4);
    float* svec     = (float*)alloc(D * 4);
    float* wsv      = (float*)alloc(D * 4);
    unsigned short* wp0 = (unsigned short*)alloc((size_t)D * D * 2 * 2);
    unsigned short* wp1 = (unsigned short*)alloc((size_t)D * D * 2 * 2);
    unsigned short* wp2 = (unsigned short*)alloc((size_t)D * D * 2 * 2);

    size_t fixed = off;
    size_t need_batched = fixed + 2 * ((size_t)2 * N * D * 2 + 512);
    bool batched = ws_size >= need_batched;
    int NB = batched ? 2 * N : N;
    int paired = batched ? 1 : 0;

    unsigned short* hbufA = (unsigned short*)alloc((size_t)NB * D * 2);
    unsigned short* hbufB = (unsigned short*)alloc((size_t)NB * D * 2);

    hipMemsetAsync(counts, 0, (size_t)N * 4, stream);
    hipMemsetAsync(hist, 0, 256 * 4, stream);
    hipMemsetAsync(svec, 0, D * 4, stream);

    pack_w<<<8, 256, 0, stream>>>(W0, wp0);
    pack_w<<<8, 256, 0, stream>>>(W1, wp1);
    pack_w<<<8, 256, 0, stream>>>(W2, wp2);

    int eblocks = (E + 255) / 256;
    int sblocks = (N + 1023) / 1024;   // 1024 elems per block
    count_kernel<<<eblocks, 256, 0, stream>>>(dst, counts, E);
    scan_reduce<<<sblocks, 256, 0, stream>>>(counts, bsum, N);
    scan_tops<<<1, 64, 0, stream>>>(bsum, bofs, row_ptr + N, sblocks);
    scan_final<<<sblocks, 256, 0, stream>>>(counts, bofs, row_ptr, cursor, N);
    fill_kernel<<<eblocks, 256, 0, stream>>>(src, dst, cursor, src_sorted, E);
    // degree-bucket permutation (LDS-aggregated counting sort)
    hist_kernel<<<sblocks, 256, 0, stream>>>(counts, hist, N);
    scan_hist<<<1, 256, 0, stream>>>(hist, binofs, bincur);
    scatter_perm<<<sblocks, 256, 0, stream>>>(counts, bincur, perm, N);

    int n4 = N * D / 4;
    int cblocks = (n4 + 255) / 256;
    int gblocks = (NB + 63) / 64;

    if (batched) {
        cvt_kernel<<<cblocks, 256, 0, stream>>>(x, hbufA, n4);
        cvt_kernel<<<cblocks, 256, 0, stream>>>(sx, hbufA + (size_t)N * D, n4);
        agg_gemm<<<gblocks, 256, 0, stream>>>(hbufA, row_ptr, src_sorted, perm, wp0, b0,
                                              hbufB, N, NB, paired, nullptr, 0, 0.f);
        agg_gemm<<<gblocks, 256, 0, stream>>>(hbufB, row_ptr, src_sorted, perm, wp1, b1,
                                              hbufA, N, NB, paired, nullptr, 0, 0.f);
        agg_gemm<<<gblocks, 256, 0, stream>>>(hbufA, row_ptr, src_sorted, perm, wp2, b2,
                                              hbufB, N, NB, paired, svec, N, inv_n);
        wd_kernel<<<1, 128, 0, stream>>>(Wd, svec, wsv);
        disc_kernel<<<(NB + 3) / 4, 256, 0, stream>>>(hbufB, wsv, out, NB);
    } else {
        auto encode = [&](const float* input, float* mean_out) {
            cvt_kernel<<<cblocks, 256, 0, stream>>>(input, hbufA, n4);
            agg_gemm<<<gblocks, 256, 0, stream>>>(hbufA, row_ptr, src_sorted, perm, wp0, b0,
                                                  hbufB, N, NB, paired, nullptr, 0, 0.f);
            agg_gemm<<<gblocks, 256, 0, stream>>>(hbufB, row_ptr, src_sorted, perm, wp1, b1,
                                                  hbufA, N, NB, paired, nullptr, 0, 0.f);
            agg_gemm<<<gblocks, 256, 0, stream>>>(hbufA, row_ptr, src_sorted, perm, wp2, b2,
                                                  hbufB, N, NB, paired, mean_out, mean_out ? N : 0, inv_n);
        };
        encode(x, svec);
        wd_kernel<<<1, 128, 0, stream>>>(Wd, svec, wsv);
        disc_kernel<<<(NB + 3) / 4, 256, 0, stream>>>(hbufB, wsv, out, NB);
        encode(sx, nullptr);
        disc_kernel<<<(NB + 3) / 4, 256, 0, stream>>>(hbufB, wsv, out + N, NB);
    }
}

// Round 11
// 298.559 us; speedup vs baseline: 2.3464x; 1.3060x over previous
//
#include <hip/hip_runtime.h>

#define D 128

typedef short bf16x8 __attribute__((ext_vector_type(8)));
typedef float f32x4 __attribute__((ext_vector_type(4)));

// bf16 helpers (finite values; RNE rounding)
static __device__ __forceinline__ unsigned short f2bf(float f) {
    unsigned int u = __float_as_uint(f);
    u = u + 0x7FFFu + ((u >> 16) & 1u);
    return (unsigned short)(u >> 16);
}
static __device__ __forceinline__ float bf2f(unsigned short h) {
    return __uint_as_float(((unsigned int)h) << 16);
}

// ---------------- CSR build ----------------

__global__ __launch_bounds__(256) void count_kernel(const int* __restrict__ dst,
        int* __restrict__ counts, int E) {
    int e = blockIdx.x * 256 + threadIdx.x;
    if (e < E) atomicAdd(&counts[dst[e]], 1);
}

__global__ __launch_bounds__(256) void scan_reduce(const int* __restrict__ counts,
        int* __restrict__ bsum, int n) {
    int b = blockIdx.x, t = threadIdx.x;
    int base = b * 1024 + t * 4;
    int s = 0;
    #pragma unroll
    for (int i = 0; i < 4; ++i) {
        int idx = base + i;
        if (idx < n) s += counts[idx];
    }
    __shared__ int sd[256];
    sd[t] = s;
    __syncthreads();
    #pragma unroll
    for (int off = 128; off > 0; off >>= 1) {
        if (t < off) sd[t] += sd[t + off];
        __syncthreads();
    }
    if (t == 0) bsum[b] = sd[0];
}

__global__ __launch_bounds__(64) void scan_tops(const int* __restrict__ bsum,
        int* __restrict__ bofs, int* __restrict__ row_ptr_end, int B) {
    int t = threadIdx.x;
    int v = (t < B) ? bsum[t] : 0;
    int inc = v;
    #pragma unroll
    for (int off = 1; off < 64; off <<= 1) {
        int u = __shfl_up(inc, off);
        if (t >= off) inc += u;
    }
    if (t < B) bofs[t] = inc - v;
    if (t == 63) *row_ptr_end = inc;
}

__global__ __launch_bounds__(256) void scan_final(const int* __restrict__ counts,
        const int* __restrict__ bofs, int* __restrict__ row_ptr,
        int* __restrict__ cursor, int n) {
    int b = blockIdx.x, t = threadIdx.x;
    int base = b * 1024 + t * 4;
    int v[4];
    int s = 0;
    #pragma unroll
    for (int i = 0; i < 4; ++i) {
        int idx = base + i;
        v[i] = (idx < n) ? counts[idx] : 0;
        s += v[i];
    }
    __shared__ int sd[256];
    sd[t] = s;
    __syncthreads();
    #pragma unroll
    for (int off = 1; off < 256; off <<= 1) {
        int u = (t >= off) ? sd[t - off] : 0;
        __syncthreads();
        sd[t] += u;
        __syncthreads();
    }
    int excl = bofs[b] + sd[t] - s;
    #pragma unroll
    for (int i = 0; i < 4; ++i) {
        int idx = base + i;
        if (idx < n) {
            row_ptr[idx] = excl;
            cursor[idx] = excl;
            excl += v[i];
        }
    }
}

__global__ __launch_bounds__(256) void fill_kernel(const int* __restrict__ src,
        const int* __restrict__ dst, int* __restrict__ cursor,
        int* __restrict__ src_sorted, int E) {
    int e = blockIdx.x * 256 + threadIdx.x;
    if (e < E) {
        int p = atomicAdd(&cursor[dst[e]], 1);
        src_sorted[p] = src[e];
    }
}

// ---------------- f32 -> bf16 bulk convert ----------------

__global__ __launch_bounds__(256) void cvt_kernel(const float* __restrict__ in,
        unsigned short* __restrict__ out, int n4) {
    int i = blockIdx.x * 256 + threadIdx.x;
    if (i < n4) {
        float4 v = ((const float4*)in)[i];
        ushort4 o;
        o.x = f2bf(v.x); o.y = f2bf(v.y); o.z = f2bf(v.z); o.w = f2bf(v.w);
        ((ushort4*)out)[i] = o;
    }
}

// ---------------- W pack: hi/lo bf16 split in MFMA B-fragment order ----------------
// B-frag for 16x16x32: lane l holds B[k0+j][n], n = ct*16 + (l&15),
// k0 = s*32 + (l>>4)*8, j=0..7. Packed: chunk ((s*8+ct)*2+hilo), 64 lanes x 16B.

__global__ __launch_bounds__(256) void pack_w(const float* __restrict__ W,
        unsigned short* __restrict__ Wp) {
    int t = blockIdx.x * 256 + threadIdx.x;   // 0..2047
    if (t >= 2048) return;
    int lane = t & 63;
    int ct = (t >> 6) & 7;
    int s = t >> 9;
    int n = ct * 16 + (lane & 15);
    int k0 = s * 32 + (lane >> 4) * 8;
    unsigned short hi[8], lo[8];
    #pragma unroll
    for (int j = 0; j < 8; ++j) {
        float f = W[(size_t)(k0 + j) * 128 + n];
        unsigned short h = f2bf(f);
        hi[j] = h;
        lo[j] = f2bf(f - bf2f(h));
    }
    size_t bh = ((size_t)((s * 8 + ct) * 2 + 0) * 64 + lane) * 8;
    size_t bl = ((size_t)((s * 8 + ct) * 2 + 1) * 64 + lane) * 8;
    #pragma unroll
    for (int j = 0; j < 8; ++j) { Wp[bh + j] = hi[j]; Wp[bl + j] = lo[j]; }
}

// ---------------- fused: Hout = relu(agg(Hin) @ W + b) [+ column mean] ----------------
// 512 threads / 64-row tile; LDS ~35 KB -> 4 blocks/CU x 8 waves = 100% occ cap.
// Phase 1 (R6-proven gather): 32 x 16-lane groups, lane reads uint4 (16B) chunk
// of the 256B src row, x4 unroll (4 loads in flight/lane), 2 nodes per group.
// f32 sums -> LDS Af[64][129].
// Phase 2 (validated R4-R6 MFMA): wave w = rows (w&3)*16, col-tiles (w>>2)*4..+4.
// Lane l: A-frag row l&15, k-chunk (l>>4)*8; split hi/lo bf16; 3 MFMA per
// (s, ct). C/D mapping: col = ct*16 + (l&15), row = (l>>4)*4 + reg.
// Nodes [N,NT) gather via row_ptr with +N offset (batched shuffled graph).

__global__ __launch_bounds__(512, 8) void agg_gemm(const unsigned short* __restrict__ Hin,
        const int* __restrict__ row_ptr, const int* __restrict__ src_sorted,
        const unsigned short* __restrict__ Wp, const float* __restrict__ bias,
        unsigned short* __restrict__ Hout, int N, int NT,
        float* __restrict__ mean_out, int Nmean, float inv_n) {
    __shared__ float Af[64][129];
    __shared__ float red[8][64];
    int tid = threadIdx.x;
    int bm = blockIdx.x * 64;

    // ---- phase 1: gather 64 nodes (32 concurrent 16-lane groups x 2 iterations)
    {
        int lane = tid & 15;    // 16B chunk within 256B row
        int ng   = tid >> 4;    // group 0..31
        const uint4* h4 = (const uint4*)Hin;

        auto addv = [](float* a, uint4 v) {
            a[0] += __uint_as_float(v.x << 16);
            a[1] += __uint_as_float(v.x & 0xFFFF0000u);
            a[2] += __uint_as_float(v.y << 16);
            a[3] += __uint_as_float(v.y & 0xFFFF0000u);
            a[4] += __uint_as_float(v.z << 16);
            a[5] += __uint_as_float(v.z & 0xFFFF0000u);
            a[6] += __uint_as_float(v.w << 16);
            a[7] += __uint_as_float(v.w & 0xFFFF0000u);
        };

        #pragma unroll
        for (int g = 0; g < 2; ++g) {
            int local = g * 32 + ng;
            int node = bm + local; if (node >= NT) node = NT - 1;
            int base = (node < N) ? 0 : N;
            int rp = node - base;
            int beg = row_ptr[rp], end = row_ptr[rp + 1];

            float acc[8];
            #pragma unroll
            for (int i = 0; i < 8; ++i) acc[i] = 0.f;

            int j = beg;
            for (; j + 3 < end; j += 4) {
                uint4 v0 = h4[(size_t)(src_sorted[j    ] + base) * 16 + lane];
                uint4 v1 = h4[(size_t)(src_sorted[j + 1] + base) * 16 + lane];
                uint4 v2 = h4[(size_t)(src_sorted[j + 2] + base) * 16 + lane];
                uint4 v3 = h4[(size_t)(src_sorted[j + 3] + base) * 16 + lane];
                addv(acc, v0); addv(acc, v1); addv(acc, v2); addv(acc, v3);
            }
            for (; j < end; ++j) {
                uint4 v0 = h4[(size_t)(src_sorted[j] + base) * 16 + lane];
                addv(acc, v0);
            }
            #pragma unroll
            for (int i = 0; i < 8; ++i) Af[local][lane * 8 + i] = acc[i];
        }
    }
    __syncthreads();

    // ---- phase 2: split-precision MFMA from LDS A-tile
    int w = tid >> 6, l = tid & 63;
    int fr = l & 15;
    int kg = l >> 4;
    int rt = w & 3;          // row tile 0..3
    int ch = w >> 2;         // col half 0..1
    int m0 = bm + rt * 16;

    f32x4 acc[4];
    #pragma unroll
    for (int cl = 0; cl < 4; ++cl) acc[cl] = (f32x4){0.f, 0.f, 0.f, 0.f};

    const float* arow = &Af[rt * 16 + fr][0];
    const uint4* wp4 = (const uint4*)Wp;

    for (int s = 0; s < 4; ++s) {
        bf16x8 a_hi, a_lo;
        #pragma unroll
        for (int jj = 0; jj < 8; ++jj) {
            float f = arow[s * 32 + kg * 8 + jj];
            unsigned short h = f2bf(f);
            a_hi[jj] = (short)h;
            a_lo[jj] = (short)f2bf(f - bf2f(h));
        }
        #pragma unroll
        for (int cl = 0; cl < 4; ++cl) {
            int ct = ch * 4 + cl;
            uint4 bhu = wp4[(size_t)((s * 8 + ct) * 2 + 0) * 64 + l];
            uint4 blu = wp4[(size_t)((s * 8 + ct) * 2 + 1) * 64 + l];
            bf16x8 b_hi, b_lo;
            *(uint4*)&b_hi = bhu;
            *(uint4*)&b_lo = blu;
            acc[cl] = __builtin_amdgcn_mfma_f32_16x16x32_bf16(a_hi, b_hi, acc[cl], 0, 0, 0);
            acc[cl] = __builtin_amdgcn_mfma_f32_16x16x32_bf16(a_lo, b_hi, acc[cl], 0, 0, 0);
            acc[cl] = __builtin_amdgcn_mfma_f32_16x16x32_bf16(a_hi, b_lo, acc[cl], 0, 0, 0);
        }
    }

    // ---- epilogue: bias + relu + bf16 store (+ column partial sums)
    float colsum[4];
    #pragma unroll
    for (int cl = 0; cl < 4; ++cl) {
        int col = (ch * 4 + cl) * 16 + fr;
        float b = bias[col];
        float cs = 0.f;
        #pragma unroll
        for (int r = 0; r < 4; ++r) {
            int m = m0 + kg * 4 + r;
            float v = fmaxf(acc[cl][r] + b, 0.f);
            if (m < NT) Hout[(size_t)m * 128 + col] = f2bf(v);
            if (m < Nmean) cs += v;
        }
        colsum[cl] = cs;
    }

    if (mean_out) {
        #pragma unroll
        for (int cl = 0; cl < 4; ++cl) {
            float v = colsum[cl];
            v += __shfl_xor(v, 16);
            v += __shfl_xor(v, 32);
            if (l < 16) red[w][cl * 16 + l] = v;
        }
        __syncthreads();
        if (tid < 128) {
            int half = tid >> 6;          // 0: cols 0-63 (waves 0-3), 1: cols 64-127 (waves 4-7)
            int cl = tid & 63;
            float s = red[half * 4 + 0][cl] + red[half * 4 + 1][cl]
                    + red[half * 4 + 2][cl] + red[half * 4 + 3][cl];
            if (s != 0.f) atomicAdd(&mean_out[tid], s * inv_n);
        }
    }
}

// ---------------- wsv = Wd @ s ----------------

__global__ __launch_bounds__(128) void wd_kernel(const float* __restrict__ Wd,
        const float* __restrict__ s, float* __restrict__ wsv) {
    __shared__ float sl[128];
    int i = threadIdx.x;
    sl[i] = s[i];
    __syncthreads();
    float acc = 0.f;
    for (int j = 0; j < 128; ++j) acc += Wd[(size_t)i * 128 + j] * sl[j];
    wsv[i] = acc;
}

// ---------------- out[i] = dot(h[i], wsv), h bf16, one wave per node ----------------

__global__ __launch_bounds__(256) void disc_kernel(const unsigned short* __restrict__ h,
        const float* __restrict__ wsv, float* __restrict__ out, int n) {
    int wave = threadIdx.x >> 6, lane = threadIdx.x & 63;
    int node = blockIdx.x * 4 + wave;
    if (node >= n) return;
    unsigned int hv = ((const unsigned int*)h)[(size_t)node * 64 + lane];
    float2 wv = *(const float2*)&wsv[lane * 2];
    float lo = __uint_as_float(hv << 16);
    float hi = __uint_as_float(hv & 0xFFFF0000u);
    float acc = lo * wv.x + hi * wv.y;
    #pragma unroll
    for (int off = 32; off > 0; off >>= 1) acc += __shfl_down(acc, off);
    if (lane == 0) out[node] = acc;
}

// ---------------- host orchestration ----------------

extern "C" void kernel_launch(void* const* d_in, const int* in_sizes, int n_in,
                              void* d_out, int out_size, void* d_ws, size_t ws_size,
                              hipStream_t stream) {
    const int* edge_index = (const int*)d_in[0];
    const float* x  = (const float*)d_in[1];
    const float* sx = (const float*)d_in[2];
    const float* W0 = (const float*)d_in[3];
    const float* b0 = (const float*)d_in[4];
    const float* W1 = (const float*)d_in[5];
    const float* b1 = (const float*)d_in[6];
    const float* W2 = (const float*)d_in[7];
    const float* b2 = (const float*)d_in[8];
    const float* Wd = (const float*)d_in[9];
    float* out = (float*)d_out;

    const int E = in_sizes[0] / 2;
    const int N = in_sizes[1] / D;
    const int* src = edge_index;
    const int* dst = edge_index + E;
    const float inv_n = 1.0f / (float)N;

    char* wsp = (char*)d_ws;
    size_t off = 0;
    auto alloc = [&](size_t bytes) -> void* {
        void* p = wsp + off;
        off += (bytes + 511) & ~(size_t)511;
        return p;
    };
    int* counts     = (int*)alloc((size_t)N * 4);
    int* row_ptr    = (int*)alloc((size_t)(N + 1) * 4);
    int* cursor     = (int*)alloc((size_t)N * 4);
    int* src_sorted = (int*)alloc((size_t)E * 4);
    int* bsum       = (int*)alloc(64 * 4);
    int* bofs       = (int*)alloc(64 * 4);
    float* svec     = (float*)alloc(D * 4);
    float* wsv      = (float*)alloc(D * 4);
    unsigned short* wp0 = (unsigned short*)alloc((size_t)D * D * 2 * 2);
    unsigned short* wp1 = (unsigned short*)alloc((size_t)D * D * 2 * 2);
    unsigned short* wp2 = (unsigned short*)alloc((size_t)D * D * 2 * 2);

    size_t fixed = off;
    size_t need_batched = fixed + 2 * ((size_t)2 * N * D * 2 + 512);
    bool batched = ws_size >= need_batched;
    int NB = batched ? 2 * N : N;

    unsigned short* hbufA = (unsigned short*)alloc((size_t)NB * D * 2);
    unsigned short* hbufB = (unsigned short*)alloc((size_t)NB * D * 2);

    hipMemsetAsync(counts, 0, (size_t)N * 4, stream);
    hipMemsetAsync(svec, 0, D * 4, stream);

    pack_w<<<8, 256, 0, stream>>>(W0, wp0);
    pack_w<<<8, 256, 0, stream>>>(W1, wp1);
    pack_w<<<8, 256, 0, stream>>>(W2, wp2);

    int eblocks = (E + 255) / 256;
    int sblocks = (N + 1023) / 1024;
    count_kernel<<<eblocks, 256, 0, stream>>>(dst, counts, E);
    scan_reduce<<<sblocks, 256, 0, stream>>>(counts, bsum, N);
    scan_tops<<<1, 64, 0, stream>>>(bsum, bofs, row_ptr + N, sblocks);
    scan_final<<<sblocks, 256, 0, stream>>>(counts, bofs, row_ptr, cursor, N);
    fill_kernel<<<eblocks, 256, 0, stream>>>(src, dst, cursor, src_sorted, E);

    int n4 = N * D / 4;
    int cblocks = (n4 + 255) / 256;
    int gblocks = (NB + 63) / 64;

    if (batched) {
        cvt_kernel<<<cblocks, 256, 0, stream>>>(x, hbufA, n4);
        cvt_kernel<<<cblocks, 256, 0, stream>>>(sx, hbufA + (size_t)N * D, n4);
        agg_gemm<<<gblocks, 512, 0, stream>>>(hbufA, row_ptr, src_sorted, wp0, b0,
                                              hbufB, N, NB, nullptr, 0, 0.f);
        agg_gemm<<<gblocks, 512, 0, stream>>>(hbufB, row_ptr, src_sorted, wp1, b1,
                                              hbufA, N, NB, nullptr, 0, 0.f);
        agg_gemm<<<gblocks, 512, 0, stream>>>(hbufA, row_ptr, src_sorted, wp2, b2,
                                              hbufB, N, NB, svec, N, inv_n);
        wd_kernel<<<1, 128, 0, stream>>>(Wd, svec, wsv);
        disc_kernel<<<(NB + 3) / 4, 256, 0, stream>>>(hbufB, wsv, out, NB);
    } else {
        auto encode = [&](const float* input, float* mean_out) {
            cvt_kernel<<<cblocks, 256, 0, stream>>>(input, hbufA, n4);
            agg_gemm<<<gblocks, 512, 0, stream>>>(hbufA, row_ptr, src_sorted, wp0, b0,
                                                  hbufB, N, NB, nullptr, 0, 0.f);
            agg_gemm<<<gblocks, 512, 0, stream>>>(hbufB, row_ptr, src_sorted, wp1, b1,
                                                  hbufA, N, NB, nullptr, 0, 0.f);
            agg_gemm<<<gblocks, 512, 0, stream>>>(hbufA, row_ptr, src_sorted, wp2, b2,
                                                  hbufB, N, NB, mean_out, mean_out ? N : 0, inv_n);
        };
        encode(x, svec);
        wd_kernel<<<1, 128, 0, stream>>>(Wd, svec, wsv);
        disc_kernel<<<(NB + 3) / 4, 256, 0, stream>>>(hbufB, wsv, out, NB);
        encode(sx, nullptr);
        disc_kernel<<<(NB + 3) / 4, 256, 0, stream>>>(hbufB, wsv, out + N, NB);
    }
}